// Round 1
// 6863.718 us; speedup vs baseline: 3.7611x; 3.7611x over previous
//
#include <hip/hip_runtime.h>
#include <hip/hip_bf16.h>

typedef short short8 __attribute__((ext_vector_type(8)));
typedef float f32x4 __attribute__((ext_vector_type(4)));
typedef unsigned short us4 __attribute__((ext_vector_type(4)));

#define AS1 __attribute__((address_space(1)))
#define AS3 __attribute__((address_space(3)))

static __device__ __forceinline__ void gl_lds16(const void* g, void* l) {
    __builtin_amdgcn_global_load_lds((const AS1 void*)g, (AS3 void*)l, 16, 0, 0);
}

static __device__ __forceinline__ unsigned short f2bf(float x) {
    __hip_bfloat16 b = __float2bfloat16(x);
    return __builtin_bit_cast(unsigned short, b);
}

// ---------------- f32 -> bf16 convert, 4 elems/thread, exact grid ----------------
__global__ void cvt_bf16_kernel(const float* __restrict__ src, unsigned short* __restrict__ dst) {
    size_t i = (size_t)blockIdx.x * 256 + threadIdx.x;
    float4 v = ((const float4*)src)[i];
    us4 o = { f2bf(v.x), f2bf(v.y), f2bf(v.z), f2bf(v.w) };
    ((us4*)dst)[i] = o;
}

// ---------------- embedding gather -> bf16, one block per token ----------------
__global__ void embed_kernel(const int* __restrict__ x, const float* __restrict__ embed,
                             unsigned short* __restrict__ Xb) {
    int m = blockIdx.x;
    int tok = x[m];
    float4 v = ((const float4*)(embed + (size_t)tok * 1024))[threadIdx.x];
    us4 o = { f2bf(v.x), f2bf(v.y), f2bf(v.z), f2bf(v.w) };
    ((us4*)(Xb + (size_t)m * 1024))[threadIdx.x] = o;
}

// ---------------- C[M,N] fp32 = A[M,K]bf16 * B[N,K]bf16^T + bias0 + bias1 ----------------
// 128x128 tile, BK=64, 256 threads = 4 waves (2x2 of 64x64), mfma 16x16x32 bf16,
// staging via global_load_lds width=16 (m97 structure).
__global__ __launch_bounds__(256) void gemm_bt_kernel(
    const unsigned short* __restrict__ A, const unsigned short* __restrict__ B,
    float* __restrict__ C, const float* __restrict__ bias0, const float* __restrict__ bias1,
    int M, int N, int K)
{
    __shared__ __align__(16) unsigned short As[128 * 64];
    __shared__ __align__(16) unsigned short Bs[128 * 64];
    const int tid = threadIdx.x;
    const int l = tid & 63, w = tid >> 6;
    const int wy = w >> 1, wx = w & 1;
    const int m0 = blockIdx.y * 128, n0 = blockIdx.x * 128;
    const int lm = l & 15, lq = l >> 4;
    f32x4 acc[4][4] = {};

    for (int kb = 0; kb < K; kb += 64) {
        __syncthreads();   // protect LDS from previous iteration's readers
        #pragma unroll
        for (int rd = 0; rd < 4; ++rd) {
            int c = rd * 256 + tid;          // 8-elem chunk id, lane-linear per wave
            int row = c >> 3, kc = c & 7;
            gl_lds16(A + (size_t)(m0 + row) * K + kb + kc * 8, As + c * 8);
            gl_lds16(B + (size_t)(n0 + row) * K + kb + kc * 8, Bs + c * 8);
        }
        __syncthreads();   // drains vmcnt (global_load_lds) per barrier semantics
        #pragma unroll
        for (int ks = 0; ks < 2; ++ks) {
            const int kk = ks * 32 + lq * 8;
            short8 a[4], b[4];
            #pragma unroll
            for (int i = 0; i < 4; ++i)
                a[i] = *(const short8*)(As + (wy * 64 + i * 16 + lm) * 64 + kk);
            #pragma unroll
            for (int i = 0; i < 4; ++i)
                b[i] = *(const short8*)(Bs + (wx * 64 + i * 16 + lm) * 64 + kk);
            #pragma unroll
            for (int mt = 0; mt < 4; ++mt)
                #pragma unroll
                for (int nt = 0; nt < 4; ++nt)
                    acc[mt][nt] = __builtin_amdgcn_mfma_f32_16x16x32_bf16(a[mt], b[nt], acc[mt][nt], 0, 0, 0);
        }
    }
    // epilogue: C/D layout col = lane&15, row = (lane>>4)*4 + reg
    #pragma unroll
    for (int nt = 0; nt < 4; ++nt) {
        int n = n0 + wx * 64 + nt * 16 + lm;
        float bv = 0.f;
        if (bias0) bv += bias0[n];
        if (bias1) bv += bias1[n];
        #pragma unroll
        for (int mt = 0; mt < 4; ++mt) {
            size_t base = (size_t)(m0 + wy * 64 + mt * 16 + lq * 4) * N + n;
            C[base]               = acc[mt][nt][0] + bv;
            C[base + (size_t)N]   = acc[mt][nt][1] + bv;
            C[base + 2*(size_t)N] = acc[mt][nt][2] + bv;
            C[base + 3*(size_t)N] = acc[mt][nt][3] + bv;
        }
    }
}

// ---------------- fused 2-layer persistent LSTM, software-pipelined ----------------
// 256 blocks x 256 threads, 1 block/CU. Block owns h-columns [blk*4, blk*4+4) of BOTH
// layers (16 gate rows each). Weight slices (Whh0, Wih1, Whh1) pre-loaded into MFMA
// A-frags (96 VGPRs). Superstep s: layer0 computes h0(s) (if s<1024), layer1 computes
// h1(s-1) (if s>=1) using the SAME staged h0(s-1) B-frags for its input projection.
// 1025 grid barriers total (vs 2048 before).
//
// Coherence design (replaces __threadfence, which emitted buffer_wbl2+buffer_inv and
// nuked the per-XCD L2 every step -> 230MB of refetch in the counters):
//   - h state exchanged via relaxed AGENT-scope atomic ull load/store (sc0 sc1,
//     write-through, L2-bypass) -- ONLY this data pays coherence cost; pre/weights
//     stay L2-cached.
//   - ordering: coherent h stores -> s_waitcnt vmcnt(0) -> __syncthreads ->
//     relaxed arrival add. Poll 16 flat group counters with a 64-lane __all ballot.
#define GSTRIDE 1056   // uints per counter row (>=1025 steps)
#define NGRP    16

__global__ __launch_bounds__(256, 2) void lstm_fused_kernel(
    const float* __restrict__ pre,            // (4,1024,4096) fp32, layer0 preacts (biases added)
    const unsigned short* __restrict__ Whh0,  // (4096,1024) bf16
    const unsigned short* __restrict__ Wih1,  // (4096,1024) bf16
    const unsigned short* __restrict__ Whh1,  // (4096,1024) bf16
    const float* __restrict__ bih1, const float* __restrict__ bhh1,
    unsigned long long* __restrict__ h0buf,   // [2][4][1024] bf16 = [2][1024] ull, pre-zeroed
    unsigned long long* __restrict__ h1buf,   // same
    unsigned* __restrict__ grp,               // [NGRP][GSTRIDE] zeroed
    unsigned short* __restrict__ hs1)         // (4,1024,1024) bf16 layer1 outputs
{
    const int tid = threadIdx.x;
    const int l = tid & 63, w = tid >> 6;
    const int blk = blockIdx.x;
    const int r = l & 15;        // A-frag m index
    const int q = l >> 4;        // quad
    const int koff = w * 256;    // wave's K slice

    // Preload A-frags for all three weight slices. Row m -> weight row
    // (m>>2)*1024 + blk*4 + (m&3)  (gate-major), k = koff + s*32 + q*8.
    short8 af0[8], afi1[8], af1[8];
    {
        const size_t rowoff = ((size_t)((r >> 2) * 1024 + blk * 4 + (r & 3))) * 1024;
        #pragma unroll
        for (int s = 0; s < 8; ++s) {
            af0[s]  = *(const short8*)(Whh0 + rowoff + koff + s * 32 + q * 8);
            afi1[s] = *(const short8*)(Wih1 + rowoff + koff + s * 32 + q * 8);
            af1[s]  = *(const short8*)(Whh1 + rowoff + koff + s * 32 + q * 8);
        }
    }

    __shared__ float zp0[4][64], zp1[4][64];          // per-wave z partials
    __shared__ __align__(16) unsigned short h0s[4][1024];  // staged h0(s-1)
    __shared__ __align__(16) unsigned short h1s[4][1024];  // staged h1(s-2)

    // finisher mappings: layer0 = tid 0..15 (wave0), layer1 = tid 64..79 (wave1)
    const int fb = l & 3, fcl = (l >> 2) & 3;   // (batch, col-within-block) for lane<16
    const int fcol = blk * 4 + fcl;
    float bsum1[4] = {0.f, 0.f, 0.f, 0.f};
    if (w == 1 && l < 16) {
        #pragma unroll
        for (int g = 0; g < 4; ++g)
            bsum1[g] = bih1[g * 1024 + fcol] + bhh1[g * 1024 + fcol];
    }
    float c0 = 0.f, c1 = 0.f;

    for (int s = 0; s <= 1024; ++s) {
        const bool L0 = (s < 1024);   // layer0 step s active
        const bool L1 = (s >= 1);     // layer1 step s-1 active

        // ---- prefetch layer0 pre-activations (normal cached loads, consumed late) ----
        float pv0 = 0.f, pv1 = 0.f, pv2 = 0.f, pv3 = 0.f;
        if (w == 0 && l < 16 && L0) {
            const float* p = pre + (((size_t)(fb * 1024 + s)) << 12) + fcol;
            pv0 = p[0]; pv1 = p[1024]; pv2 = p[2048]; pv3 = p[3072];
        }

        // ---- stage h (coherent agent loads, L2-bypass) -> LDS ----
        // h0(s-1) in slot s&1; h1(s-2) in slot (s+1)&1. Barrier at end of prev
        // superstep guarantees these stores have completed.
        {
            const unsigned long long* s0p = h0buf + (size_t)(s & 1) * 1024;
            const unsigned long long* s1p = h1buf + (size_t)((s + 1) & 1) * 1024;
            unsigned long long t0[4], t1[4];
            #pragma unroll
            for (int j = 0; j < 4; ++j)
                t0[j] = __hip_atomic_load(s0p + j * 256 + tid, __ATOMIC_RELAXED, __HIP_MEMORY_SCOPE_AGENT);
            #pragma unroll
            for (int j = 0; j < 4; ++j)
                t1[j] = __hip_atomic_load(s1p + j * 256 + tid, __ATOMIC_RELAXED, __HIP_MEMORY_SCOPE_AGENT);
            #pragma unroll
            for (int j = 0; j < 4; ++j)
                ((unsigned long long*)h0s)[j * 256 + tid] = t0[j];
            #pragma unroll
            for (int j = 0; j < 4; ++j)
                ((unsigned long long*)h1s)[j * 256 + tid] = t1[j];
        }
        __syncthreads();

        // ---- MFMAs: B[n=lane&15 -> batch lane&3][k=q*8+j] from staged h ----
        f32x4 acc0 = {0.f, 0.f, 0.f, 0.f}, acc1 = {0.f, 0.f, 0.f, 0.f};
        {
            const unsigned short* hr0 = &h0s[0][0] + (l & 3) * 1024 + koff + q * 8;
            const unsigned short* hr1 = &h1s[0][0] + (l & 3) * 1024 + koff + q * 8;
            #pragma unroll
            for (int k = 0; k < 8; ++k) {
                short8 bf = *(const short8*)(hr0 + k * 32);
                if (L0) acc0 = __builtin_amdgcn_mfma_f32_16x16x32_bf16(af0[k],  bf, acc0, 0, 0, 0);
                if (L1) acc1 = __builtin_amdgcn_mfma_f32_16x16x32_bf16(afi1[k], bf, acc1, 0, 0, 0);
            }
            if (L1) {
                #pragma unroll
                for (int k = 0; k < 8; ++k) {
                    short8 bf = *(const short8*)(hr1 + k * 32);
                    acc1 = __builtin_amdgcn_mfma_f32_16x16x32_bf16(af1[k], bf, acc1, 0, 0, 0);
                }
            }
        }
        if (r < 4) {   // D cols 0..3 = batches; D row = q*4+reg
            #pragma unroll
            for (int i = 0; i < 4; ++i) {
                zp0[w][(q * 4 + i) * 4 + r] = acc0[i];
                zp1[w][(q * 4 + i) * 4 + r] = acc1[i];
            }
        }
        __syncthreads();

        // ---- layer0 finisher (wave0 lanes 0..15): h0(s) ----
        if (w == 0 && l < 16 && L0) {
            float z[4];
            #pragma unroll
            for (int g = 0; g < 4; ++g) {
                int row = g * 4 + fcl;
                z[g] = zp0[0][row*4+fb] + zp0[1][row*4+fb] + zp0[2][row*4+fb] + zp0[3][row*4+fb];
            }
            z[0] += pv0; z[1] += pv1; z[2] += pv2; z[3] += pv3;
            float ig = 1.f / (1.f + __expf(-z[0]));
            float fg = 1.f / (1.f + __expf(-z[1]));
            float gg = tanhf(z[2]);
            float og = 1.f / (1.f + __expf(-z[3]));
            c0 = fg * c0 + ig * gg;
            float h = og * tanhf(c0);
            int hv = (int)f2bf(h);
            // pack 4 cols of one batch into a ull via shfl; lane p (<4) stores batch p
            int x0 = __shfl(hv, l + 0);
            int x1 = __shfl(hv, l + 4);
            int x2 = __shfl(hv, l + 8);
            int x3 = __shfl(hv, l + 12);
            if (l < 4) {
                unsigned long long pk = (unsigned long long)(unsigned short)x0
                                      | ((unsigned long long)(unsigned short)x1 << 16)
                                      | ((unsigned long long)(unsigned short)x2 << 32)
                                      | ((unsigned long long)(unsigned short)x3 << 48);
                __hip_atomic_store(h0buf + (size_t)((s + 1) & 1) * 1024 + l * 256 + blk, pk,
                                   __ATOMIC_RELAXED, __HIP_MEMORY_SCOPE_AGENT);
            }
        }
        // ---- layer1 finisher (wave1 lanes 0..15): h1(s-1) ----
        if (w == 1 && l < 16 && L1) {
            const int u = s - 1;
            float z[4];
            #pragma unroll
            for (int g = 0; g < 4; ++g) {
                int row = g * 4 + fcl;
                z[g] = zp1[0][row*4+fb] + zp1[1][row*4+fb] + zp1[2][row*4+fb] + zp1[3][row*4+fb] + bsum1[g];
            }
            float ig = 1.f / (1.f + __expf(-z[0]));
            float fg = 1.f / (1.f + __expf(-z[1]));
            float gg = tanhf(z[2]);
            float og = 1.f / (1.f + __expf(-z[3]));
            c1 = fg * c1 + ig * gg;
            float h = og * tanhf(c1);
            unsigned short hu = f2bf(h);
            hs1[((size_t)(fb * 1024 + u) << 10) + fcol] = hu;   // normal cached store
            int hv = (int)hu;
            int x0 = __shfl(hv, l + 0);
            int x1 = __shfl(hv, l + 4);
            int x2 = __shfl(hv, l + 8);
            int x3 = __shfl(hv, l + 12);
            if (l < 4) {
                unsigned long long pk = (unsigned long long)(unsigned short)x0
                                      | ((unsigned long long)(unsigned short)x1 << 16)
                                      | ((unsigned long long)(unsigned short)x2 << 32)
                                      | ((unsigned long long)(unsigned short)x3 << 48);
                __hip_atomic_store(h1buf + (size_t)(s & 1) * 1024 + l * 256 + blk, pk,
                                   __ATOMIC_RELAXED, __HIP_MEMORY_SCOPE_AGENT);
            }
        }

        // drain coherent h stores to the device coherence point (per-wave; waves 2/3 no-op)
        asm volatile("s_waitcnt vmcnt(0)" ::: "memory");
        __syncthreads();   // cross-wave: arrival below happens only after ALL h stores drained

        // ---- flat grid barrier: 16 counters x 16 blocks, 64-lane ballot poll ----
        if (w == 0) {
            if (l == 0)
                __hip_atomic_fetch_add(&grp[(blk & 15) * GSTRIDE + s], 1u,
                                       __ATOMIC_RELAXED, __HIP_MEMORY_SCOPE_AGENT);
            int guard = 0;
            for (;;) {
                unsigned v = __hip_atomic_load(&grp[(l & 15) * GSTRIDE + s],
                                               __ATOMIC_RELAXED, __HIP_MEMORY_SCOPE_AGENT);
                if (__all((int)(v >= 16u))) break;
                __builtin_amdgcn_s_sleep(1);
                if (++guard > (1 << 15)) break;   // anti-hang safeguard
            }
        }
        __syncthreads();
    }
}

extern "C" void kernel_launch(void* const* d_in, const int* in_sizes, int n_in,
                              void* d_out, int out_size, void* d_ws, size_t ws_size,
                              hipStream_t stream)
{
    const int*   x     = (const int*)d_in[0];
    const float* embed = (const float*)d_in[1];
    const float* Wproj = (const float*)d_in[2];
    const float* bproj = (const float*)d_in[3];
    const float* Wih0  = (const float*)d_in[4];
    const float* Whh0  = (const float*)d_in[5];
    const float* bih0  = (const float*)d_in[6];
    const float* bhh0  = (const float*)d_in[7];
    const float* Wih1  = (const float*)d_in[8];
    const float* Whh1  = (const float*)d_in[9];
    const float* bih1  = (const float*)d_in[10];
    const float* bhh1  = (const float*)d_in[11];

    char* ws = (char*)d_ws;
    unsigned* grp = (unsigned*)ws;                                  // 16*1056*4 = 67584
    unsigned long long* h0buf = (unsigned long long*)(ws + 69632);  // 16384
    unsigned long long* h1buf = (unsigned long long*)(ws + 86016);  // 16384 -> end 102400

    size_t off = (size_t)1 << 20;
    auto alloc = [&](size_t bytes) { void* p = ws + off; off += (bytes + 255) & ~(size_t)255; return p; };
    unsigned short* Xb     = (unsigned short*)alloc(4096ull * 1024 * 2);
    unsigned short* hs1    = (unsigned short*)alloc(4096ull * 1024 * 2);
    unsigned short* wih0b  = (unsigned short*)alloc(4096ull * 1024 * 2);
    unsigned short* whh0b  = (unsigned short*)alloc(4096ull * 1024 * 2);
    unsigned short* wih1b  = (unsigned short*)alloc(4096ull * 1024 * 2);
    unsigned short* whh1b  = (unsigned short*)alloc(4096ull * 1024 * 2);
    unsigned short* wprojb = (unsigned short*)alloc(32000ull * 1024 * 2);
    float* pre             = (float*)alloc(4096ull * 4096 * 4);     // layer0 only

    // zero barrier counters + h double-buffers (ws is poisoned 0xAA before every call)
    hipMemsetAsync(d_ws, 0, 102400, stream);

    cvt_bf16_kernel<<<4096, 256, 0, stream>>>(Wih0, wih0b);
    cvt_bf16_kernel<<<4096, 256, 0, stream>>>(Whh0, whh0b);
    cvt_bf16_kernel<<<4096, 256, 0, stream>>>(Wih1, wih1b);
    cvt_bf16_kernel<<<4096, 256, 0, stream>>>(Whh1, whh1b);
    cvt_bf16_kernel<<<32000, 256, 0, stream>>>(Wproj, wprojb);
    embed_kernel<<<4096, 256, 0, stream>>>(x, embed, Xb);

    // layer0 input projection (pre-activations, biases fused)
    gemm_bt_kernel<<<dim3(32, 32), 256, 0, stream>>>(Xb, wih0b, pre, bih0, bhh0, 4096, 4096, 1024);
    // fused 2-layer recurrence (layer1 input projection computed in-kernel)
    lstm_fused_kernel<<<256, 256, 0, stream>>>(pre, whh0b, wih1b, whh1b, bih1, bhh1,
                                               h0buf, h1buf, grp, hs1);
    // projection
    gemm_bt_kernel<<<dim3(250, 32), 256, 0, stream>>>(hs1, wprojb, (float*)d_out, bproj, nullptr, 4096, 32000, 1024);
}